// Round 1
// baseline (477.464 us; speedup 1.0000x reference)
//
#include <hip/hip_runtime.h>

// EdgeConv fused pipeline, MI355X gfx950.
// Structure: edges of node n are [16n,16n+16) and share xi  => one wave per node,
// 16x16x32 bf16 MFMA tiles. BN is training-mode over all E=1.6M edges => 3 passes
// with global stats between them (full recompute; ws use ~130KB only).
// b1/b2 cancel inside BN (v - mean(v)) and are ignored.

#define N_NODES 100000
#define KE 16
#define E_EDGES (N_NODES * KE)
#define BN_EPS 1e-5f

typedef __attribute__((ext_vector_type(8))) short bf16x8;  // 8 bf16 (4 VGPRs)
typedef __attribute__((ext_vector_type(4))) float f32x4;   // MFMA C/D

#define MFMA(a, b, c) __builtin_amdgcn_mfma_f32_16x16x32_bf16((a), (b), (c), 0, 0, 0)

__device__ __forceinline__ short bf16b(float f) {
  union { float f; unsigned u; } v;
  v.f = f;
  unsigned r = v.u + 0x7fffu + ((v.u >> 16) & 1u);  // RNE
  return (short)(r >> 16);
}

__device__ __forceinline__ void pack8(bf16x8& d, float4 a, float4 b) {
  d[0] = bf16b(a.x); d[1] = bf16b(a.y); d[2] = bf16b(a.z); d[3] = bf16b(a.w);
  d[4] = bf16b(b.x); d[5] = bf16b(b.y); d[6] = bf16b(b.z); d[7] = bf16b(b.w);
}

__device__ __forceinline__ float4 sub4(float4 a, float4 b) {
  return make_float4(a.x - b.x, a.y - b.y, a.z - b.z, a.w - b.w);
}

// ---- weight packing into MFMA B-fragment order -----------------------------
// wp[(s*4+t)*64 + l] holds 8 bf16: B[k=32s + (l>>4)*8 + j][c=16t + (l&15)]
__global__ void pack_w(const float* __restrict__ W1, const float* __restrict__ W2,
                       short* __restrict__ wp1, short* __restrict__ wp2) {
  int tid = blockIdx.x * blockDim.x + threadIdx.x;
  if (tid < 1024) {  // W1: 4 k-steps x 4 n-tiles x 64 lanes
    int l = tid & 63, st = tid >> 6;
    int s = st >> 2, t = st & 3;
    int quad = l >> 4, n16 = l & 15;
    for (int j = 0; j < 8; j++) {
      int k = 32 * s + quad * 8 + j, c = 16 * t + n16;
      wp1[tid * 8 + j] = bf16b(W1[k * 64 + c]);
    }
  } else if (tid < 1536) {  // W2: 2 k-steps x 4 n-tiles x 64 lanes
    int e = tid - 1024;
    int l = e & 63, st = e >> 6;
    int s = st >> 2, t = st & 3;
    int quad = l >> 4, n16 = l & 15;
    for (int j = 0; j < 8; j++) {
      int k = 32 * s + quad * 8 + j, c = 16 * t + n16;
      wp2[e * 8 + j] = bf16b(W2[k * 64 + c]);
    }
  }
}

// ---- GEMM1: one wave computes h1_pre[16 edges][64 ch] for node n -----------
// A[m][k]: k<64 -> xi[k] (same for all m); k>=64 -> xj[m][k-64]-xi[k-64].
// A-frag: lane holds A[m=l&15][k = 32*s + (l>>4)*8 + j].
__device__ __forceinline__ void gemm1_wave(const float* __restrict__ x,
                                           const int* __restrict__ ecol,
                                           const bf16x8* __restrict__ wp1,
                                           int n, int l, int quad, int n16,
                                           f32x4 acc[4]) {
  const float* xr = x + (size_t)n * 64 + quad * 8;
  float4 xi0 = *(const float4*)(xr);
  float4 xi1 = *(const float4*)(xr + 4);
  float4 xi2 = *(const float4*)(xr + 32);
  float4 xi3 = *(const float4*)(xr + 36);
  int cj = ecol[n * KE + n16];
  const float* xc = x + (size_t)cj * 64 + quad * 8;
  float4 xj0 = *(const float4*)(xc);
  float4 xj1 = *(const float4*)(xc + 4);
  float4 xj2 = *(const float4*)(xc + 32);
  float4 xj3 = *(const float4*)(xc + 36);

  bf16x8 fa0, fa1, fa2, fa3;
  pack8(fa0, xi0, xi1);                          // k-step 0: xi[0:32)
  pack8(fa1, xi2, xi3);                          // k-step 1: xi[32:64)
  pack8(fa2, sub4(xj0, xi0), sub4(xj1, xi1));    // k-step 2: d[0:32)
  pack8(fa3, sub4(xj2, xi2), sub4(xj3, xi3));    // k-step 3: d[32:64)

#pragma unroll
  for (int t = 0; t < 4; t++) {
    f32x4 a = {0.f, 0.f, 0.f, 0.f};
    a = MFMA(fa0, wp1[(0 + t) * 64 + l], a);
    a = MFMA(fa1, wp1[(4 + t) * 64 + l], a);
    a = MFMA(fa2, wp1[(8 + t) * 64 + l], a);
    a = MFMA(fa3, wp1[(12 + t) * 64 + l], a);
    acc[t] = a;
  }
}

// ---- BN1+ReLU then GEMM2 (D-layout -> A-layout via per-wave LDS tile) ------
// tile row stride 72 bf16 = 144 B: keeps ds_read_b128 16B-aligned, breaks
// power-of-2 bank stride.
__device__ __forceinline__ void layer2_wave(const bf16x8* __restrict__ wp2,
                                            const float* __restrict__ bn1,
                                            short* myt, int l, int quad, int n16,
                                            const f32x4 acc1[4], f32x4 acc2[4]) {
#pragma unroll
  for (int t = 0; t < 4; t++) {
    int c = 16 * t + n16;
    float a = bn1[c], b = bn1[64 + c];
#pragma unroll
    for (int r = 0; r < 4; r++) {
      float h = fmaxf(acc1[t][r] * a + b, 0.f);  // BN1 + ReLU
      myt[(quad * 4 + r) * 72 + c] = bf16b(h);   // D: row=quad*4+r, col=16t+n16
    }
  }
  // A2-frag: lane reads row m=n16, k = 32*s + quad*8 + j (8 contiguous bf16)
  bf16x8 f0 = *(bf16x8*)(myt + n16 * 72 + quad * 8);
  bf16x8 f1 = *(bf16x8*)(myt + n16 * 72 + 32 + quad * 8);
#pragma unroll
  for (int t = 0; t < 4; t++) {
    f32x4 a = {0.f, 0.f, 0.f, 0.f};
    a = MFMA(f0, wp2[(0 + t) * 64 + l], a);
    a = MFMA(f1, wp2[(4 + t) * 64 + l], a);
    acc2[t] = a;
  }
}

// ---- per-block stats reduce: quad-shuffle -> LDS atomics -> spread global --
__device__ __forceinline__ void stats_reduce(const f32x4 acc[4], int quad, int n16,
                                             float* lstat) {
#pragma unroll
  for (int t = 0; t < 4; t++) {
    float s = acc[t][0] + acc[t][1] + acc[t][2] + acc[t][3];
    float q = acc[t][0] * acc[t][0] + acc[t][1] * acc[t][1] +
              acc[t][2] * acc[t][2] + acc[t][3] * acc[t][3];
    s += __shfl_xor(s, 16); s += __shfl_xor(s, 32);
    q += __shfl_xor(q, 16); q += __shfl_xor(q, 32);
    if (quad == 0) {
      atomicAdd(&lstat[16 * t + n16], s);
      atomicAdd(&lstat[64 + 16 * t + n16], q);
    }
  }
}

__global__ __launch_bounds__(256) void k_stats1(const float* __restrict__ x,
                                                const int* __restrict__ ecol,
                                                const bf16x8* __restrict__ wp1,
                                                float* __restrict__ gacc) {
  __shared__ float lstat[128];
  int tid = threadIdx.x;
  if (tid < 128) lstat[tid] = 0.f;
  __syncthreads();
  int wave = tid >> 6, l = tid & 63, quad = l >> 4, n16 = l & 15;
  int n = blockIdx.x * 4 + wave;  // grid 25000 x 4 waves covers N exactly
  f32x4 acc[4];
  gemm1_wave(x, ecol, wp1, n, l, quad, n16, acc);
  stats_reduce(acc, quad, n16, lstat);
  __syncthreads();
  if (tid < 128) atomicAdd(&gacc[(blockIdx.x & 63) * 128 + tid], lstat[tid]);
}

__global__ void k_finalize(const float* __restrict__ gacc, const float* __restrict__ g,
                           const float* __restrict__ be, float* __restrict__ bn) {
  int c = threadIdx.x;  // 64 threads
  float s = 0.f, q = 0.f;
  for (int i = 0; i < 64; i++) {
    s += gacc[i * 128 + c];
    q += gacc[i * 128 + 64 + c];
  }
  float mean = s * (1.0f / E_EDGES);
  float var = q * (1.0f / E_EDGES) - mean * mean;  // biased, matches reference
  float rstd = rsqrtf(var + BN_EPS);
  float a = g[c] * rstd;
  bn[c] = a;
  bn[64 + c] = be[c] - mean * a;  // bn(v) = v*a + b
}

__global__ __launch_bounds__(256) void k_stats2(const float* __restrict__ x,
                                                const int* __restrict__ ecol,
                                                const bf16x8* __restrict__ wp1,
                                                const bf16x8* __restrict__ wp2,
                                                const float* __restrict__ bn1,
                                                float* __restrict__ gacc) {
  __shared__ float lstat[128];
  __shared__ __align__(16) short tile[4][16 * 72];
  int tid = threadIdx.x;
  if (tid < 128) lstat[tid] = 0.f;
  __syncthreads();
  int wave = tid >> 6, l = tid & 63, quad = l >> 4, n16 = l & 15;
  int n = blockIdx.x * 4 + wave;
  f32x4 acc1[4];
  gemm1_wave(x, ecol, wp1, n, l, quad, n16, acc1);
  f32x4 acc2[4];
  layer2_wave(wp2, bn1, &tile[wave][0], l, quad, n16, acc1, acc2);
  stats_reduce(acc2, quad, n16, lstat);
  __syncthreads();
  if (tid < 128) atomicAdd(&gacc[(blockIdx.x & 63) * 128 + tid], lstat[tid]);
}

__global__ __launch_bounds__(256) void k_final(const float* __restrict__ x,
                                               const int* __restrict__ ecol,
                                               const bf16x8* __restrict__ wp1,
                                               const bf16x8* __restrict__ wp2,
                                               const float* __restrict__ bn1,
                                               const float* __restrict__ bn2,
                                               float* __restrict__ out) {
  __shared__ __align__(16) short tile[4][16 * 72];
  int tid = threadIdx.x, wave = tid >> 6, l = tid & 63, quad = l >> 4, n16 = l & 15;
  int n = blockIdx.x * 4 + wave;
  f32x4 acc1[4];
  gemm1_wave(x, ecol, wp1, n, l, quad, n16, acc1);
  f32x4 acc2[4];
  layer2_wave(wp2, bn1, &tile[wave][0], l, quad, n16, acc1, acc2);
  float vt[4];
#pragma unroll
  for (int t = 0; t < 4; t++) {
    int c = 16 * t + n16;
    float a = bn2[c], b = bn2[64 + c];
    float v = 0.f;  // relu floor: max(0, max_m h) == max_m relu(h)
#pragma unroll
    for (int r = 0; r < 4; r++) v = fmaxf(v, acc2[t][r] * a + b);
    v = fmaxf(v, __shfl_xor(v, 16));  // combine quads -> max over all 16 edges
    v = fmaxf(v, __shfl_xor(v, 32));
    vt[t] = v;
  }
  float vout = (quad == 0) ? vt[0] : (quad == 1) ? vt[1] : (quad == 2) ? vt[2] : vt[3];
  out[(size_t)n * 64 + l] = vout;  // lane l writes channel l: coalesced 256B/row
}

extern "C" void kernel_launch(void* const* d_in, const int* in_sizes, int n_in,
                              void* d_out, int out_size, void* d_ws, size_t ws_size,
                              hipStream_t stream) {
  const float* x   = (const float*)d_in[0];
  // d_in[1] = edge_row: structurally repeat(arange(N),16), unused
  const int*   ec  = (const int*)d_in[2];
  const float* W1  = (const float*)d_in[3];
  // d_in[4] = b1: cancels in BN, unused
  const float* g1  = (const float*)d_in[5];
  const float* be1 = (const float*)d_in[6];
  const float* W2  = (const float*)d_in[7];
  // d_in[8] = b2: cancels in BN, unused
  const float* g2  = (const float*)d_in[9];
  const float* be2 = (const float*)d_in[10];
  float* out = (float*)d_out;

  char* ws = (char*)d_ws;
  bf16x8* wp1  = (bf16x8*)(ws);            // 16 KB packed W1
  bf16x8* wp2  = (bf16x8*)(ws + 16384);    // 8 KB packed W2
  float* gacc1 = (float*)(ws + 24576);     // 64 slots x 128 = 32 KB
  float* gacc2 = (float*)(ws + 24576 + 32768);
  float* bn1   = (float*)(ws + 24576 + 65536);        // a[64], b[64]
  float* bn2   = (float*)(ws + 24576 + 65536 + 512);

  // ws is re-poisoned to 0xAA before every launch: zero the accumulators
  hipMemsetAsync(gacc1, 0, 65536, stream);

  hipLaunchKernelGGL(pack_w, dim3(6), dim3(256), 0, stream, W1, W2,
                     (short*)wp1, (short*)wp2);
  hipLaunchKernelGGL(k_stats1, dim3(25000), dim3(256), 0, stream, x, ec, wp1, gacc1);
  hipLaunchKernelGGL(k_finalize, dim3(1), dim3(64), 0, stream, gacc1, g1, be1, bn1);
  hipLaunchKernelGGL(k_stats2, dim3(25000), dim3(256), 0, stream, x, ec, wp1, wp2,
                     bn1, gacc2);
  hipLaunchKernelGGL(k_finalize, dim3(1), dim3(64), 0, stream, gacc2, g2, be2, bn2);
  hipLaunchKernelGGL(k_final, dim3(25000), dim3(256), 0, stream, x, ec, wp1, wp2,
                     bn1, bn2, out);
}

// Round 2
// 353.153 us; speedup vs baseline: 1.3520x; 1.3520x over previous
//
#include <hip/hip_runtime.h>

// EdgeConv fused pipeline, MI355X gfx950 — round 2.
// R1 post-mortem: all three passes latency-bound on the random xj gather
// (HBM 16%, MFMA 11%, VALU 34%, occ 41% — nothing saturated). R2:
//  (a) pass 1 stores h1_pre (bf16, 205 MB) to ws; passes 2/3 become pure
//      streaming reads in MFMA-A-fragment-friendly row-major layout.
//  (b) pass 1 pipelines the ecol->xj chain (2-stage, grid-stride waves).
//  (c) HW bf16 cvt (v_cvt_pk_bf16_f32) replaces 4-op software RNE pack.
// Fallback to the R1 3x-recompute structure if ws_size is too small.

#define N_NODES 100000
#define KE 16
#define E_EDGES (N_NODES * KE)
#define BN_EPS 1e-5f

typedef __attribute__((ext_vector_type(8))) short bf16x8;  // 8 bf16 (4 VGPRs)
typedef __attribute__((ext_vector_type(4))) float f32x4;   // MFMA C/D
typedef __attribute__((ext_vector_type(4))) int i32x4;

#define MFMA(a, b, c) __builtin_amdgcn_mfma_f32_16x16x32_bf16((a), (b), (c), 0, 0, 0)

static __device__ __forceinline__ short bf16b(float f) {
  __bf16 h = (__bf16)f;  // fptrunc RNE -> v_cvt_pk_bf16_f32 on gfx950
  return __builtin_bit_cast(short, h);
}

#if __has_builtin(__builtin_amdgcn_cvt_pk_bf16_f32)
static __device__ __forceinline__ int pk2(float a, float b) {
  return __builtin_bit_cast(int, __builtin_amdgcn_cvt_pk_bf16_f32(a, b));
}
#else
static __device__ __forceinline__ int pk2(float a, float b) {
  return (int)(unsigned short)bf16b(a) | ((int)(unsigned short)bf16b(b) << 16);
}
#endif

static __device__ __forceinline__ bf16x8 pack8(float4 a, float4 b) {
  i32x4 v = {pk2(a.x, a.y), pk2(a.z, a.w), pk2(b.x, b.y), pk2(b.z, b.w)};
  return __builtin_bit_cast(bf16x8, v);
}

static __device__ __forceinline__ float bf2f(short s) {
  unsigned u = ((unsigned)(unsigned short)s) << 16;
  return __builtin_bit_cast(float, u);
}

static __device__ __forceinline__ float4 sub4(float4 a, float4 b) {
  return make_float4(a.x - b.x, a.y - b.y, a.z - b.z, a.w - b.w);
}

// ---- weight packing into MFMA B-fragment order -----------------------------
// wp[(s*4+t)*64 + l] holds 8 bf16: B[k=32s + (l>>4)*8 + j][c=16t + (l&15)]
__global__ void pack_w(const float* __restrict__ W1, const float* __restrict__ W2,
                       short* __restrict__ wp1, short* __restrict__ wp2) {
  int tid = blockIdx.x * blockDim.x + threadIdx.x;
  if (tid < 1024) {  // W1: 4 k-steps x 4 n-tiles x 64 lanes
    int l = tid & 63, st = tid >> 6;
    int s = st >> 2, t = st & 3;
    int quad = l >> 4, n16 = l & 15;
    for (int j = 0; j < 8; j++) {
      int k = 32 * s + quad * 8 + j, c = 16 * t + n16;
      wp1[tid * 8 + j] = bf16b(W1[k * 64 + c]);
    }
  } else if (tid < 1536) {  // W2: 2 k-steps x 4 n-tiles x 64 lanes
    int e = tid - 1024;
    int l = e & 63, st = e >> 6;
    int s = st >> 2, t = st & 3;
    int quad = l >> 4, n16 = l & 15;
    for (int j = 0; j < 8; j++) {
      int k = 32 * s + quad * 8 + j, c = 16 * t + n16;
      wp2[e * 8 + j] = bf16b(W2[k * 64 + c]);
    }
  }
}

// ---- gather + GEMM1 building blocks ---------------------------------------
struct NL { float4 xi[4]; float4 xj[4]; };

static __device__ __forceinline__ void issue_loads(const float* __restrict__ x,
                                                   const int* __restrict__ ecol,
                                                   int n, int quad, int n16, NL& L) {
  const float* xr = x + (size_t)n * 64 + quad * 8;
  L.xi[0] = *(const float4*)(xr);
  L.xi[1] = *(const float4*)(xr + 4);
  L.xi[2] = *(const float4*)(xr + 32);
  L.xi[3] = *(const float4*)(xr + 36);
  int cj = ecol[n * KE + n16];
  const float* xc = x + (size_t)cj * 64 + quad * 8;
  L.xj[0] = *(const float4*)(xc);
  L.xj[1] = *(const float4*)(xc + 4);
  L.xj[2] = *(const float4*)(xc + 32);
  L.xj[3] = *(const float4*)(xc + 36);
}

static __device__ __forceinline__ void gemm1_from(const NL& L,
                                                  const bf16x8* __restrict__ wp1,
                                                  int l, f32x4 acc[4]) {
  bf16x8 fa0 = pack8(L.xi[0], L.xi[1]);                        // xi[0:32)
  bf16x8 fa1 = pack8(L.xi[2], L.xi[3]);                        // xi[32:64)
  bf16x8 fa2 = pack8(sub4(L.xj[0], L.xi[0]), sub4(L.xj[1], L.xi[1]));
  bf16x8 fa3 = pack8(sub4(L.xj[2], L.xi[2]), sub4(L.xj[3], L.xi[3]));
#pragma unroll
  for (int t = 0; t < 4; t++) {
    f32x4 a = {0.f, 0.f, 0.f, 0.f};
    a = MFMA(fa0, wp1[(0 + t) * 64 + l], a);
    a = MFMA(fa1, wp1[(4 + t) * 64 + l], a);
    a = MFMA(fa2, wp1[(8 + t) * 64 + l], a);
    a = MFMA(fa3, wp1[(12 + t) * 64 + l], a);
    acc[t] = a;
  }
}

static __device__ __forceinline__ void gemm1_wave(const float* __restrict__ x,
                                                  const int* __restrict__ ecol,
                                                  const bf16x8* __restrict__ wp1,
                                                  int n, int l, int quad, int n16,
                                                  f32x4 acc[4]) {
  NL L;
  issue_loads(x, ecol, n, quad, n16, L);
  gemm1_from(L, wp1, l, acc);
}

// ---- per-block stats reduce: quad-shuffle -> LDS atomics -> spread global --
static __device__ __forceinline__ void stats_reduce(const f32x4 acc[4], int quad,
                                                    int n16, float* lstat) {
#pragma unroll
  for (int t = 0; t < 4; t++) {
    float s = acc[t][0] + acc[t][1] + acc[t][2] + acc[t][3];
    float q = acc[t][0] * acc[t][0] + acc[t][1] * acc[t][1] +
              acc[t][2] * acc[t][2] + acc[t][3] * acc[t][3];
    s += __shfl_xor(s, 16); s += __shfl_xor(s, 32);
    q += __shfl_xor(q, 16); q += __shfl_xor(q, 32);
    if (quad == 0) {
      atomicAdd(&lstat[16 * t + n16], s);
      atomicAdd(&lstat[64 + 16 * t + n16], q);
    }
  }
}

// ---- pass 1: gather + GEMM1 + stats1 + store h1_pre (bf16, row-major) ------
__global__ __launch_bounds__(256, 3) void k_pass1(const float* __restrict__ x,
                                                  const int* __restrict__ ecol,
                                                  const bf16x8* __restrict__ wp1,
                                                  float* __restrict__ gacc,
                                                  short* __restrict__ h1) {
  __shared__ float lstat[128];
  __shared__ __align__(16) short tiles[4][16 * 72];
  int tid = threadIdx.x;
  if (tid < 128) lstat[tid] = 0.f;
  __syncthreads();
  int wave = tid >> 6, l = tid & 63, quad = l >> 4, n16 = l & 15;
  short* myt = &tiles[wave][0];
  int NW = gridDim.x * 4;
  int n = blockIdx.x * 4 + wave;
  NL A;
  if (n < N_NODES) issue_loads(x, ecol, n, quad, n16, A);
  while (n < N_NODES) {
    int nn = n + NW;
    NL B;
    if (nn < N_NODES) issue_loads(x, ecol, nn, quad, n16, B);  // pipelined
    f32x4 acc[4];
    gemm1_from(A, wp1, l, acc);
    stats_reduce(acc, quad, n16, lstat);
    // D-layout -> row-major bf16 via per-wave LDS tile (stride 72: 16B-aligned
    // rows, 2-way bank aliasing only)
#pragma unroll
    for (int t = 0; t < 4; t++) {
      int c = 16 * t + n16;
#pragma unroll
      for (int r = 0; r < 4; r++) myt[(quad * 4 + r) * 72 + c] = bf16b(acc[t][r]);
    }
    bf16x8 v0 = *(bf16x8*)(myt + (l >> 2) * 72 + (l & 3) * 16);
    bf16x8 v1 = *(bf16x8*)(myt + (l >> 2) * 72 + (l & 3) * 16 + 8);
    short* dst = h1 + (size_t)n * 1024 + l * 16;  // node tile = contiguous 2KB
    *(bf16x8*)(dst) = v0;
    *(bf16x8*)(dst + 8) = v1;
    A = B;
    n = nn;
  }
  __syncthreads();
  if (tid < 128) atomicAdd(&gacc[(blockIdx.x & 63) * 128 + tid], lstat[tid]);
}

// ---- BN stats finalize -----------------------------------------------------
__global__ void k_finalize(const float* __restrict__ gacc, const float* __restrict__ g,
                           const float* __restrict__ be, float* __restrict__ bn) {
  int c = threadIdx.x;  // 64 threads
  float s = 0.f, q = 0.f;
  for (int i = 0; i < 64; i++) {
    s += gacc[i * 128 + c];
    q += gacc[i * 128 + 64 + c];
  }
  float mean = s * (1.0f / E_EDGES);
  float var = q * (1.0f / E_EDGES) - mean * mean;  // biased, matches reference
  float rstd = rsqrtf(var + BN_EPS);
  float a = g[c] * rstd;
  bn[c] = a;
  bn[64 + c] = be[c] - mean * a;  // bn(v) = v*a + b
}

// ---- passes 2/3: stream h1, BN1+ReLU, GEMM2, then stats2 or output ---------
template <int FINAL>
__global__ __launch_bounds__(256, 4) void k_layer2(const short* __restrict__ h1,
                                                   const bf16x8* __restrict__ wp2,
                                                   const float* __restrict__ bn1,
                                                   const float* __restrict__ bn2,
                                                   float* __restrict__ gacc,
                                                   float* __restrict__ out) {
  __shared__ float lstat[128];
  int tid = threadIdx.x;
  if (FINAL == 0) {
    if (tid < 128) lstat[tid] = 0.f;
    __syncthreads();
  }
  int wave = tid >> 6, l = tid & 63, quad = l >> 4, n16 = l & 15;
  // loop-invariant BN1 coeffs for this lane's 16 k-channels
  float a0[8], b0[8], a1[8], b1[8];
#pragma unroll
  for (int j = 0; j < 8; j++) {
    int c0 = quad * 8 + j, c1 = 32 + quad * 8 + j;
    a0[j] = bn1[c0]; b0[j] = bn1[64 + c0];
    a1[j] = bn1[c1]; b1[j] = bn1[64 + c1];
  }
  float a2[4], b2v[4];
  if (FINAL) {
#pragma unroll
    for (int t = 0; t < 4; t++) {
      a2[t] = bn2[16 * t + n16];
      b2v[t] = bn2[64 + 16 * t + n16];
    }
  }
  int NW = gridDim.x * 4;
  int n = blockIdx.x * 4 + wave;
  bf16x8 r0, r1;
  if (n < N_NODES) {
    const short* row = h1 + (size_t)n * 1024 + n16 * 64 + quad * 8;
    r0 = *(const bf16x8*)(row);
    r1 = *(const bf16x8*)(row + 32);
  }
  while (n < N_NODES) {
    int nn = n + NW;
    bf16x8 s0, s1;
    if (nn < N_NODES) {  // prefetch next node
      const short* row = h1 + (size_t)nn * 1024 + n16 * 64 + quad * 8;
      s0 = *(const bf16x8*)(row);
      s1 = *(const bf16x8*)(row + 32);
    }
    // BN1 + ReLU + repack to A-fragments
    i32x4 w0, w1;
#pragma unroll
    for (int j = 0; j < 8; j += 2) {
      float u0 = fmaxf(fmaf(bf2f(r0[j]), a0[j], b0[j]), 0.f);
      float u1 = fmaxf(fmaf(bf2f(r0[j + 1]), a0[j + 1], b0[j + 1]), 0.f);
      w0[j >> 1] = pk2(u0, u1);
      float v0 = fmaxf(fmaf(bf2f(r1[j]), a1[j], b1[j]), 0.f);
      float v1 = fmaxf(fmaf(bf2f(r1[j + 1]), a1[j + 1], b1[j + 1]), 0.f);
      w1[j >> 1] = pk2(v0, v1);
    }
    bf16x8 f0 = __builtin_bit_cast(bf16x8, w0);
    bf16x8 f1 = __builtin_bit_cast(bf16x8, w1);
    f32x4 acc[4];
#pragma unroll
    for (int t = 0; t < 4; t++) {
      f32x4 a = {0.f, 0.f, 0.f, 0.f};
      a = MFMA(f0, wp2[(0 + t) * 64 + l], a);
      a = MFMA(f1, wp2[(4 + t) * 64 + l], a);
      acc[t] = a;
    }
    if (FINAL == 0) {
      stats_reduce(acc, quad, n16, lstat);
    } else {
      float vt[4];
#pragma unroll
      for (int t = 0; t < 4; t++) {
        float v = 0.f;  // relu floor: max(0, max_m h) == max_m relu(h)
#pragma unroll
        for (int r = 0; r < 4; r++) v = fmaxf(v, fmaf(acc[t][r], a2[t], b2v[t]));
        v = fmaxf(v, __shfl_xor(v, 16));
        v = fmaxf(v, __shfl_xor(v, 32));
        vt[t] = v;
      }
      float vout = (quad == 0) ? vt[0] : (quad == 1) ? vt[1] : (quad == 2) ? vt[2] : vt[3];
      out[(size_t)n * 64 + l] = vout;  // lane l == channel l: coalesced
    }
    r0 = s0; r1 = s1;
    n = nn;
  }
  if (FINAL == 0) {
    __syncthreads();
    if (tid < 128) atomicAdd(&gacc[(blockIdx.x & 63) * 128 + tid], lstat[tid]);
  }
}

// ---- fallback (ws too small): R1 3x-recompute structure --------------------
static __device__ __forceinline__ void layer2_wave(const bf16x8* __restrict__ wp2,
                                                   const float* __restrict__ bn1,
                                                   short* myt, int l, int quad, int n16,
                                                   const f32x4 acc1[4], f32x4 acc2[4]) {
#pragma unroll
  for (int t = 0; t < 4; t++) {
    int c = 16 * t + n16;
    float a = bn1[c], b = bn1[64 + c];
#pragma unroll
    for (int r = 0; r < 4; r++) {
      float h = fmaxf(acc1[t][r] * a + b, 0.f);
      myt[(quad * 4 + r) * 72 + c] = bf16b(h);
    }
  }
  bf16x8 f0 = *(bf16x8*)(myt + n16 * 72 + quad * 8);
  bf16x8 f1 = *(bf16x8*)(myt + n16 * 72 + 32 + quad * 8);
#pragma unroll
  for (int t = 0; t < 4; t++) {
    f32x4 a = {0.f, 0.f, 0.f, 0.f};
    a = MFMA(f0, wp2[(0 + t) * 64 + l], a);
    a = MFMA(f1, wp2[(4 + t) * 64 + l], a);
    acc2[t] = a;
  }
}

__global__ __launch_bounds__(256) void k_stats1(const float* __restrict__ x,
                                                const int* __restrict__ ecol,
                                                const bf16x8* __restrict__ wp1,
                                                float* __restrict__ gacc) {
  __shared__ float lstat[128];
  int tid = threadIdx.x;
  if (tid < 128) lstat[tid] = 0.f;
  __syncthreads();
  int wave = tid >> 6, l = tid & 63, quad = l >> 4, n16 = l & 15;
  int n = blockIdx.x * 4 + wave;
  f32x4 acc[4];
  gemm1_wave(x, ecol, wp1, n, l, quad, n16, acc);
  stats_reduce(acc, quad, n16, lstat);
  __syncthreads();
  if (tid < 128) atomicAdd(&gacc[(blockIdx.x & 63) * 128 + tid], lstat[tid]);
}

__global__ __launch_bounds__(256) void k_stats2(const float* __restrict__ x,
                                                const int* __restrict__ ecol,
                                                const bf16x8* __restrict__ wp1,
                                                const bf16x8* __restrict__ wp2,
                                                const float* __restrict__ bn1,
                                                float* __restrict__ gacc) {
  __shared__ float lstat[128];
  __shared__ __align__(16) short tile[4][16 * 72];
  int tid = threadIdx.x;
  if (tid < 128) lstat[tid] = 0.f;
  __syncthreads();
  int wave = tid >> 6, l = tid & 63, quad = l >> 4, n16 = l & 15;
  int n = blockIdx.x * 4 + wave;
  f32x4 acc1[4];
  gemm1_wave(x, ecol, wp1, n, l, quad, n16, acc1);
  f32x4 acc2[4];
  layer2_wave(wp2, bn1, &tile[wave][0], l, quad, n16, acc1, acc2);
  stats_reduce(acc2, quad, n16, lstat);
  __syncthreads();
  if (tid < 128) atomicAdd(&gacc[(blockIdx.x & 63) * 128 + tid], lstat[tid]);
}

__global__ __launch_bounds__(256) void k_final(const float* __restrict__ x,
                                               const int* __restrict__ ecol,
                                               const bf16x8* __restrict__ wp1,
                                               const bf16x8* __restrict__ wp2,
                                               const float* __restrict__ bn1,
                                               const float* __restrict__ bn2,
                                               float* __restrict__ out) {
  __shared__ __align__(16) short tile[4][16 * 72];
  int tid = threadIdx.x, wave = tid >> 6, l = tid & 63, quad = l >> 4, n16 = l & 15;
  int n = blockIdx.x * 4 + wave;
  f32x4 acc1[4];
  gemm1_wave(x, ecol, wp1, n, l, quad, n16, acc1);
  f32x4 acc2[4];
  layer2_wave(wp2, bn1, &tile[wave][0], l, quad, n16, acc1, acc2);
  float vt[4];
#pragma unroll
  for (int t = 0; t < 4; t++) {
    int c = 16 * t + n16;
    float a = bn2[c], b = bn2[64 + c];
    float v = 0.f;
#pragma unroll
    for (int r = 0; r < 4; r++) v = fmaxf(v, acc2[t][r] * a + b);
    v = fmaxf(v, __shfl_xor(v, 16));
    v = fmaxf(v, __shfl_xor(v, 32));
    vt[t] = v;
  }
  float vout = (quad == 0) ? vt[0] : (quad == 1) ? vt[1] : (quad == 2) ? vt[2] : vt[3];
  out[(size_t)n * 64 + l] = vout;
}

extern "C" void kernel_launch(void* const* d_in, const int* in_sizes, int n_in,
                              void* d_out, int out_size, void* d_ws, size_t ws_size,
                              hipStream_t stream) {
  const float* x   = (const float*)d_in[0];
  // d_in[1] = edge_row: structurally repeat(arange(N),16), unused
  const int*   ec  = (const int*)d_in[2];
  const float* W1  = (const float*)d_in[3];
  // d_in[4] = b1: cancels in BN, unused
  const float* g1  = (const float*)d_in[5];
  const float* be1 = (const float*)d_in[6];
  const float* W2  = (const float*)d_in[7];
  // d_in[8] = b2: cancels in BN, unused
  const float* g2  = (const float*)d_in[9];
  const float* be2 = (const float*)d_in[10];
  float* out = (float*)d_out;

  char* ws = (char*)d_ws;
  bf16x8* wp1  = (bf16x8*)(ws);            // 16 KB packed W1
  bf16x8* wp2  = (bf16x8*)(ws + 16384);    // 8 KB packed W2
  float* gacc1 = (float*)(ws + 24576);     // 64 slots x 128 = 32 KB
  float* gacc2 = (float*)(ws + 57344);     // 32 KB
  float* bn1   = (float*)(ws + 90112);     // a[64], b[64]
  float* bn2   = (float*)(ws + 90624);
  short* h1    = (short*)(ws + 98304);     // [E][64] bf16 = 204.8 MB

  const size_t need = 98304 + (size_t)E_EDGES * 64 * 2;

  // ws is re-poisoned to 0xAA before every launch: zero the accumulators
  hipMemsetAsync(gacc1, 0, 65536, stream);
  hipLaunchKernelGGL(pack_w, dim3(6), dim3(256), 0, stream, W1, W2,
                     (short*)wp1, (short*)wp2);

  if (ws_size >= need) {
    hipLaunchKernelGGL(k_pass1, dim3(1600), dim3(256), 0, stream, x, ec, wp1,
                       gacc1, h1);
    hipLaunchKernelGGL(k_finalize, dim3(1), dim3(64), 0, stream, gacc1, g1, be1, bn1);
    hipLaunchKernelGGL((k_layer2<0>), dim3(2048), dim3(256), 0, stream, h1, wp2,
                       bn1, (const float*)nullptr, gacc2, (float*)nullptr);
    hipLaunchKernelGGL(k_finalize, dim3(1), dim3(64), 0, stream, gacc2, g2, be2, bn2);
    hipLaunchKernelGGL((k_layer2<1>), dim3(2048), dim3(256), 0, stream, h1, wp2,
                       bn1, bn2, (float*)nullptr, out);
  } else {
    hipLaunchKernelGGL(k_stats1, dim3(25000), dim3(256), 0, stream, x, ec, wp1, gacc1);
    hipLaunchKernelGGL(k_finalize, dim3(1), dim3(64), 0, stream, gacc1, g1, be1, bn1);
    hipLaunchKernelGGL(k_stats2, dim3(25000), dim3(256), 0, stream, x, ec, wp1, wp2,
                       bn1, gacc2);
    hipLaunchKernelGGL(k_finalize, dim3(1), dim3(64), 0, stream, gacc2, g2, be2, bn2);
    hipLaunchKernelGGL(k_final, dim3(25000), dim3(256), 0, stream, x, ec, wp1, wp2,
                       bn1, bn2, out);
  }
}

// Round 3
// 332.071 us; speedup vs baseline: 1.4378x; 1.0635x over previous
//
#include <hip/hip_runtime.h>

// EdgeConv fused pipeline, MI355X gfx950 — round 3.
// R2 post-mortem: pass1 FETCH=194MB vs 25.6MB input -> h1 write stream evicted
// x from L3; gather ran at HBM latency with a serialized ecol->xj chain.
// R3: no h1 buffer (pass2 re-gathers; compute is free), gather bf16 (12.8MB,
// cache-resident), weight-split removes xj-xi (raw bf16 A-frag loads), ecol
// chunks staged in LDS (breaks dependent-load chain), per-node max/min of
// h2_pre stored so the final pass is trivially elementwise. ws ~38MB.

#define N_NODES 100000
#define KE 16
#define E_EDGES (N_NODES * KE)
#define BN_EPS 1e-5f
#define NCHUNK (N_NODES / KE)      // 6250 16-node wave-chunks (exact)
#define PASS_BLOCKS ((NCHUNK + 3) / 4)

typedef __attribute__((ext_vector_type(8))) short bf16x8;  // 8 bf16 (4 VGPRs)
typedef __attribute__((ext_vector_type(4))) float f32x4;   // MFMA C/D
typedef __attribute__((ext_vector_type(4))) int i32x4;

#define MFMA(a, b, c) __builtin_amdgcn_mfma_f32_16x16x32_bf16((a), (b), (c), 0, 0, 0)

static __device__ __forceinline__ short bf16b(float f) {
  __bf16 h = (__bf16)f;  // RNE, hardware cvt on gfx950
  return __builtin_bit_cast(short, h);
}

#if __has_builtin(__builtin_amdgcn_cvt_pk_bf16_f32)
static __device__ __forceinline__ int pk2(float a, float b) {
  return __builtin_bit_cast(int, __builtin_amdgcn_cvt_pk_bf16_f32(a, b));
}
#else
static __device__ __forceinline__ int pk2(float a, float b) {
  return (int)(unsigned short)bf16b(a) | ((int)(unsigned short)bf16b(b) << 16);
}
#endif

static __device__ __forceinline__ bf16x8 pack8(float4 a, float4 b) {
  i32x4 v = {pk2(a.x, a.y), pk2(a.z, a.w), pk2(b.x, b.y), pk2(b.z, b.w)};
  return __builtin_bit_cast(bf16x8, v);
}

static __device__ __forceinline__ float bf2f(short s) {
  unsigned u = ((unsigned)(unsigned short)s) << 16;
  return __builtin_bit_cast(float, u);
}

// ---- x -> bf16 (one-time; 12.8 MB result stays L2/L3-resident) -------------
__global__ __launch_bounds__(256) void k_cvt(const float* __restrict__ x,
                                             short* __restrict__ xb) {
  int g = blockIdx.x * 256 + threadIdx.x;  // 800000 threads, 8 elems each
  const float4* x4 = (const float4*)x;
  float4 f0 = x4[2 * g], f1 = x4[2 * g + 1];
  bf16x8 v = pack8(f0, f1);
  *(bf16x8*)(xb + g * 8) = v;
}

// ---- weight packing into MFMA B-fragment order -----------------------------
// wp[(s*4+t)*64 + l] holds 8 bf16: B[k=32s + (l>>4)*8 + j][c=16t + (l&15)]
// Weight split: k-steps 0,1 (xi operand) get Wd = W1[:64]-W1[64:];
// k-steps 2,3 (xj operand) get Wb = W1[64:]. Then no xj-xi subtraction needed.
__global__ void pack_w(const float* __restrict__ W1, const float* __restrict__ W2,
                       short* __restrict__ wp1, short* __restrict__ wp2) {
  int tid = blockIdx.x * blockDim.x + threadIdx.x;
  if (tid < 1024) {  // W1: 4 k-steps x 4 n-tiles x 64 lanes
    int l = tid & 63, st = tid >> 6;
    int s = st >> 2, t = st & 3;
    int quad = l >> 4, n16 = l & 15;
    for (int j = 0; j < 8; j++) {
      int k = 32 * s + quad * 8 + j, c = 16 * t + n16;
      float w = (s < 2) ? (W1[k * 64 + c] - W1[(k + 64) * 64 + c])
                        : W1[k * 64 + c];  // k in [64,128) here
      wp1[tid * 8 + j] = bf16b(w);
    }
  } else if (tid < 1536) {  // W2: 2 k-steps x 4 n-tiles x 64 lanes
    int e = tid - 1024;
    int l = e & 63, st = e >> 6;
    int s = st >> 2, t = st & 3;
    int quad = l >> 4, n16 = l & 15;
    for (int j = 0; j < 8; j++) {
      int k = 32 * s + quad * 8 + j, c = 16 * t + n16;
      wp2[e * 8 + j] = bf16b(W2[k * 64 + c]);
    }
  }
}

// ---- gather stage: raw bf16 A-fragments (no conversion, no subtraction) ----
struct Stage { bf16x8 xi0, xi1, xj0, xj1; };

static __device__ __forceinline__ void ld_stage(const short* __restrict__ xb,
                                                int n, int cj, int quad, Stage& S) {
  const short* pi = xb + n * 64 + quad * 8;
  S.xi0 = *(const bf16x8*)(pi);
  S.xi1 = *(const bf16x8*)(pi + 32);
  const short* pj = xb + (size_t)cj * 64 + quad * 8;
  S.xj0 = *(const bf16x8*)(pj);
  S.xj1 = *(const bf16x8*)(pj + 32);
}

static __device__ __forceinline__ void gemm1(const Stage& S, const bf16x8 wf[16],
                                             f32x4 acc[4]) {
#pragma unroll
  for (int t = 0; t < 4; t++) {
    f32x4 a = {0.f, 0.f, 0.f, 0.f};
    a = MFMA(S.xi0, wf[0 + t], a);   // xi[0:32)  x Wd
    a = MFMA(S.xi1, wf[4 + t], a);   // xi[32:64) x Wd
    a = MFMA(S.xj0, wf[8 + t], a);   // xj[0:32)  x Wb
    a = MFMA(S.xj1, wf[12 + t], a);  // xj[32:64) x Wb
    acc[t] = a;
  }
}

static __device__ __forceinline__ void stat_acc(const f32x4 acc[4], float sacc[4],
                                                float qacc[4]) {
#pragma unroll
  for (int t = 0; t < 4; t++) {
    sacc[t] += (acc[t][0] + acc[t][1]) + (acc[t][2] + acc[t][3]);
    qacc[t] = fmaf(acc[t][0], acc[t][0],
              fmaf(acc[t][1], acc[t][1],
              fmaf(acc[t][2], acc[t][2],
              fmaf(acc[t][3], acc[t][3], qacc[t]))));
  }
}

static __device__ __forceinline__ void stat_flush(float sacc[4], float qacc[4],
                                                  int quad, int n16, float* lstat) {
#pragma unroll
  for (int t = 0; t < 4; t++) {
    float s = sacc[t], q = qacc[t];
    s += __shfl_xor(s, 16); s += __shfl_xor(s, 32);
    q += __shfl_xor(q, 16); q += __shfl_xor(q, 32);
    if (quad == 0) {
      atomicAdd(&lstat[16 * t + n16], s);
      atomicAdd(&lstat[64 + 16 * t + n16], q);
    }
  }
}

// ---- pass 1: gather + GEMM1 + stats1 (no stores -> no L3 pollution) --------
__global__ __launch_bounds__(256) void k_pass1(const short* __restrict__ xb,
                                               const int* __restrict__ ecol,
                                               const bf16x8* __restrict__ wp1,
                                               float* __restrict__ gacc) {
  __shared__ float lstat[128];
  __shared__ int eblk[4][256];
  int tid = threadIdx.x;
  if (tid < 128) lstat[tid] = 0.f;
  __syncthreads();
  int wave = tid >> 6, l = tid & 63, quad = l >> 4, n16 = l & 15;
  bf16x8 wf[16];
#pragma unroll
  for (int u = 0; u < 16; u++) wf[u] = wp1[u * 64 + l];  // hoisted: 64 VGPR
  float sacc[4] = {0.f, 0.f, 0.f, 0.f}, qacc[4] = {0.f, 0.f, 0.f, 0.f};
  int w = blockIdx.x * 4 + wave;
  if (w < NCHUNK) {
    int nb = w * 16;
    int* eb = eblk[wave];
    ((int4*)eb)[l] = ((const int4*)ecol)[(size_t)w * 64 + l];  // 256 idx -> LDS
    Stage SA, SB;
    ld_stage(xb, nb + 0, eb[n16], quad, SA);
    ld_stage(xb, nb + 1, eb[16 + n16], quad, SB);
#pragma unroll
    for (int i = 0; i < 16; i++) {
      f32x4 acc[4];
      gemm1(SA, wf, acc);
      stat_acc(acc, sacc, qacc);
      SA = SB;
      if (i + 2 < 16) ld_stage(xb, nb + i + 2, eb[16 * (i + 2) + n16], quad, SB);
    }
  }
  stat_flush(sacc, qacc, quad, n16, lstat);
  __syncthreads();
  if (tid < 128) atomicAdd(&gacc[(blockIdx.x & 63) * 128 + tid], lstat[tid]);
}

// ---- BN stats finalize -----------------------------------------------------
__global__ void k_finalize(const float* __restrict__ gacc, const float* __restrict__ g,
                           const float* __restrict__ be, float* __restrict__ bn) {
  int c = threadIdx.x;  // 64 threads
  float s = 0.f, q = 0.f;
  for (int i = 0; i < 64; i++) {
    s += gacc[i * 128 + c];
    q += gacc[i * 128 + 64 + c];
  }
  float mean = s * (1.0f / E_EDGES);
  float var = q * (1.0f / E_EDGES) - mean * mean;  // biased, matches reference
  float rstd = rsqrtf(var + BN_EPS);
  float a = g[c] * rstd;
  bn[c] = a;
  bn[64 + c] = be[c] - mean * a;  // bn(v) = v*a + b
}

// ---- pass 2: re-gather + GEMM1 + BN1/ReLU + GEMM2 + stats2 + node min/max --
__global__ __launch_bounds__(256) void k_pass2(const short* __restrict__ xb,
                                               const int* __restrict__ ecol,
                                               const bf16x8* __restrict__ wp1,
                                               const bf16x8* __restrict__ wp2,
                                               const float* __restrict__ bn1,
                                               float* __restrict__ gacc,
                                               short* __restrict__ hmax,
                                               short* __restrict__ hmin) {
  __shared__ float lstat[128];
  __shared__ int eblk[4][256];
  __shared__ __align__(16) short tiles[4][16 * 72];  // D->A transpose, stride 72
  int tid = threadIdx.x;
  if (tid < 128) lstat[tid] = 0.f;
  __syncthreads();
  int wave = tid >> 6, l = tid & 63, quad = l >> 4, n16 = l & 15;
  bf16x8 wf1[16], wf2[8];
#pragma unroll
  for (int u = 0; u < 16; u++) wf1[u] = wp1[u * 64 + l];
#pragma unroll
  for (int u = 0; u < 8; u++) wf2[u] = wp2[u * 64 + l];
  float a1c[4], b1c[4];
#pragma unroll
  for (int t = 0; t < 4; t++) {
    a1c[t] = bn1[16 * t + n16];
    b1c[t] = bn1[64 + 16 * t + n16];
  }
  float sacc[4] = {0.f, 0.f, 0.f, 0.f}, qacc[4] = {0.f, 0.f, 0.f, 0.f};
  short* myt = &tiles[wave][0];
  int w = blockIdx.x * 4 + wave;
  if (w < NCHUNK) {
    int nb = w * 16;
    int* eb = eblk[wave];
    ((int4*)eb)[l] = ((const int4*)ecol)[(size_t)w * 64 + l];
    Stage SA, SB;
    ld_stage(xb, nb + 0, eb[n16], quad, SA);
    ld_stage(xb, nb + 1, eb[16 + n16], quad, SB);
#pragma unroll
    for (int i = 0; i < 16; i++) {
      f32x4 acc1[4];
      gemm1(SA, wf1, acc1);
      SA = SB;
      if (i + 2 < 16) ld_stage(xb, nb + i + 2, eb[16 * (i + 2) + n16], quad, SB);
      // BN1 + ReLU, D-layout -> row-major bf16 tile (per-wave, no barrier)
#pragma unroll
      for (int t = 0; t < 4; t++) {
        int c = 16 * t + n16;
#pragma unroll
        for (int r = 0; r < 4; r++) {
          float h = fmaxf(fmaf(acc1[t][r], a1c[t], b1c[t]), 0.f);
          myt[(quad * 4 + r) * 72 + c] = bf16b(h);
        }
      }
      bf16x8 f0 = *(bf16x8*)(myt + n16 * 72 + quad * 8);
      bf16x8 f1 = *(bf16x8*)(myt + n16 * 72 + 32 + quad * 8);
      f32x4 acc2[4];
#pragma unroll
      for (int t = 0; t < 4; t++) {
        f32x4 a = {0.f, 0.f, 0.f, 0.f};
        a = MFMA(f0, wf2[0 + t], a);
        a = MFMA(f1, wf2[4 + t], a);
        acc2[t] = a;
      }
      stat_acc(acc2, sacc, qacc);
      // per-node, per-channel max & min of h2_pre over the 16 edges
      float vmx[4], vmn[4];
#pragma unroll
      for (int t = 0; t < 4; t++) {
        float mx = fmaxf(fmaxf(acc2[t][0], acc2[t][1]), fmaxf(acc2[t][2], acc2[t][3]));
        float mn = fminf(fminf(acc2[t][0], acc2[t][1]), fminf(acc2[t][2], acc2[t][3]));
        mx = fmaxf(mx, __shfl_xor(mx, 16)); mx = fmaxf(mx, __shfl_xor(mx, 32));
        mn = fminf(mn, __shfl_xor(mn, 16)); mn = fminf(mn, __shfl_xor(mn, 32));
        vmx[t] = mx; vmn[t] = mn;
      }
      int n = nb + i;
      float ox = (quad == 0) ? vmx[0] : (quad == 1) ? vmx[1] : (quad == 2) ? vmx[2] : vmx[3];
      float on = (quad == 0) ? vmn[0] : (quad == 1) ? vmn[1] : (quad == 2) ? vmn[2] : vmn[3];
      hmax[(size_t)n * 64 + l] = bf16b(ox);  // lane l == channel l: coalesced
      hmin[(size_t)n * 64 + l] = bf16b(on);
    }
  }
  stat_flush(sacc, qacc, quad, n16, lstat);
  __syncthreads();
  if (tid < 128) atomicAdd(&gacc[(blockIdx.x & 63) * 128 + tid], lstat[tid]);
}

// ---- pass 3: elementwise BN2 + ReLU + sign-select of stored min/max --------
// max_m relu(a*h+b) = relu(a>=0 ? a*hmax+b : a*hmin+b)  (affine+relu monotone)
__global__ __launch_bounds__(256) void k_pass3(const short* __restrict__ hmax,
                                               const short* __restrict__ hmin,
                                               const float* __restrict__ bn2,
                                               float* __restrict__ out) {
  int g = blockIdx.x * 256 + threadIdx.x;  // 1.6M threads, 4 channels each
  int base = g * 4;
  int c4 = base & 63;
  short4 mx4 = *(const short4*)(hmax + base);
  short4 mn4 = *(const short4*)(hmin + base);
  float4 a4 = *(const float4*)(bn2 + c4);
  float4 b4 = *(const float4*)(bn2 + 64 + c4);
  float4 o;
  o.x = fmaxf(a4.x >= 0.f ? fmaf(a4.x, bf2f(mx4.x), b4.x) : fmaf(a4.x, bf2f(mn4.x), b4.x), 0.f);
  o.y = fmaxf(a4.y >= 0.f ? fmaf(a4.y, bf2f(mx4.y), b4.y) : fmaf(a4.y, bf2f(mn4.y), b4.y), 0.f);
  o.z = fmaxf(a4.z >= 0.f ? fmaf(a4.z, bf2f(mx4.z), b4.z) : fmaf(a4.z, bf2f(mn4.z), b4.z), 0.f);
  o.w = fmaxf(a4.w >= 0.f ? fmaf(a4.w, bf2f(mx4.w), b4.w) : fmaf(a4.w, bf2f(mn4.w), b4.w), 0.f);
  *(float4*)(out + base) = o;
}

extern "C" void kernel_launch(void* const* d_in, const int* in_sizes, int n_in,
                              void* d_out, int out_size, void* d_ws, size_t ws_size,
                              hipStream_t stream) {
  const float* x   = (const float*)d_in[0];
  // d_in[1] = edge_row: structurally repeat(arange(N),16), unused
  const int*   ec  = (const int*)d_in[2];
  const float* W1  = (const float*)d_in[3];
  // d_in[4] = b1: cancels in BN, unused
  const float* g1  = (const float*)d_in[5];
  const float* be1 = (const float*)d_in[6];
  const float* W2  = (const float*)d_in[7];
  // d_in[8] = b2: cancels in BN, unused
  const float* g2  = (const float*)d_in[9];
  const float* be2 = (const float*)d_in[10];
  float* out = (float*)d_out;

  char* ws = (char*)d_ws;
  bf16x8* wp1  = (bf16x8*)(ws);                 // 16 KB packed W1 (split)
  bf16x8* wp2  = (bf16x8*)(ws + 16384);         // 8 KB packed W2
  float* gacc1 = (float*)(ws + 24576);          // 64 slots x 128 = 32 KB
  float* gacc2 = (float*)(ws + 57344);          // 32 KB
  float* bn1   = (float*)(ws + 90112);          // a[64], b[64]
  float* bn2   = (float*)(ws + 90624);
  short* xb    = (short*)(ws + 98304);          // x in bf16: 12.8 MB
  short* hmax  = (short*)(ws + 98304 + 12800000);         // 12.8 MB
  short* hmin  = (short*)(ws + 98304 + 2 * 12800000);     // 12.8 MB
  // total ws need ~38.5 MB (R2 proved >=205 MB available)

  // ws is re-poisoned to 0xAA before every launch: zero the stat accumulators
  hipMemsetAsync(gacc1, 0, 65536, stream);

  hipLaunchKernelGGL(pack_w, dim3(6), dim3(256), 0, stream, W1, W2,
                     (short*)wp1, (short*)wp2);
  hipLaunchKernelGGL(k_cvt, dim3(3125), dim3(256), 0, stream, x, xb);
  hipLaunchKernelGGL(k_pass1, dim3(PASS_BLOCKS), dim3(256), 0, stream,
                     xb, ec, wp1, gacc1);
  hipLaunchKernelGGL(k_finalize, dim3(1), dim3(64), 0, stream, gacc1, g1, be1, bn1);
  hipLaunchKernelGGL(k_pass2, dim3(PASS_BLOCKS), dim3(256), 0, stream,
                     xb, ec, wp1, wp2, bn1, gacc2, hmax, hmin);
  hipLaunchKernelGGL(k_finalize, dim3(1), dim3(64), 0, stream, gacc2, g2, be2, bn2);
  hipLaunchKernelGGL(k_pass3, dim3(6250), dim3(256), 0, stream, hmax, hmin, bn2, out);
}